// Round 4
// baseline (515.546 us; speedup 1.0000x reference)
//
#include <hip/hip_runtime.h>

// ---- problem constants ----
#define H_     8
#define DM_    1024
#define NQKV_  4096
#define ROWS_  16384          // SLEN*BSZ = 256*64
#define PAIRS_ 512            // BSZ*H
#define SCALE_ 0.08838834764831845f
#define LN_EPS_ 1e-5f

typedef __attribute__((ext_vector_type(8))) short short8;   // 8 bf16 (4 VGPRs)
typedef __attribute__((ext_vector_type(4))) float floatx4;  // MFMA accumulator

__device__ __forceinline__ float b2f(unsigned short u) {
  union { unsigned int i; float f; } v; v.i = ((unsigned int)u) << 16; return v.f;
}
__device__ __forceinline__ unsigned short f2b(float f) {
  union { unsigned int i; float f; } v; v.f = f;
  unsigned int b = v.i;
  b += 0x7FFFu + ((b >> 16) & 1u);   // round-to-nearest-even
  return (unsigned short)(b >> 16);
}

// ---- async stage with XOR bank swizzle (256 threads, 128x64 tile) ----
__device__ __forceinline__ void stage_async(const unsigned short* __restrict__ g,
                                            size_t ld, unsigned short* s, int tid) {
#pragma unroll
  for (int p = 0; p < 4; ++p) {
    int idx = p * 256 + tid;
    int r = idx >> 3, j = idx & 7;
    int cg = j ^ (r & 7);
    __builtin_amdgcn_global_load_lds(
        (const __attribute__((address_space(1))) unsigned int*)(g + (size_t)r * ld + cg * 8),
        (__attribute__((address_space(3))) unsigned int*)(s + (size_t)idx * 8),
        16, 0, 0);
  }
}
__device__ __forceinline__ short8 lds_frag(const unsigned short* s, int row, int cg) {
  return *(const short8*)(s + row * 64 + ((cg ^ (row & 7)) << 3));
}

// =====================================================================
// K0: fused fp32 -> bf16 convert of h, Wqkv, Wo (8 elems/thread)
// =====================================================================
__global__ __launch_bounds__(256) void cvt_all(const float* __restrict__ h,
                                               const float* __restrict__ wq,
                                               const float* __restrict__ wo,
                                               unsigned short* __restrict__ hb,
                                               unsigned short* __restrict__ wqb,
                                               unsigned short* __restrict__ wob) {
  int i = blockIdx.x * 256 + threadIdx.x;
  const float* src; unsigned short* dst; int off;
  if (i < 2097152)      { src = h;  dst = hb;  off = i; }
  else if (i < 2621440) { src = wq; dst = wqb; off = i - 2097152; }
  else                  { src = wo; dst = wob; off = i - 2621440; }
  const float4* s4 = (const float4*)(src + (size_t)off * 8);
  float4 v0 = s4[0], v1 = s4[1];
  union { short8 v; unsigned short u[8]; } pk;
  pk.u[0] = f2b(v0.x); pk.u[1] = f2b(v0.y); pk.u[2] = f2b(v0.z); pk.u[3] = f2b(v0.w);
  pk.u[4] = f2b(v1.x); pk.u[5] = f2b(v1.y); pk.u[6] = f2b(v1.z); pk.u[7] = f2b(v1.w);
  *(short8*)(dst + (size_t)off * 8) = pk.v;
}

// =====================================================================
// K1: qkv gemm, 128x128 tile, m97 structure, 4 blocks/CU.
//   LDS = union(staging 32KB, epilogue T[128][136] 34KB) = 34816 B ->
//   4 blocks/CU, 16 waves/CU: independent blocks overlap each other's
//   barrier drains (the m114 mechanism the 256^2/1-block variant lacked).
//   grid (32,128): bx -> n0 = bx*128 (one 128-col part: part=bx&3, hh=bx>>2);
//   by: bb = by&63, lhalf = by>>6.  2x2 waves, acc[4][4].
//   Epilogue: phi with wave-pair row-sum exchange (parts 0..2); V transpose.
// =====================================================================
__global__ __launch_bounds__(256, 4) void qkv_gemm(const unsigned short* __restrict__ A,
                                                   const unsigned short* __restrict__ B,
                                                   unsigned short* __restrict__ QKV) {
  __shared__ alignas(16) unsigned short Sh[17408];   // As|Bs staging; reused as T[128][136]
  unsigned short* As = Sh;
  unsigned short* Bs = Sh + 8192;
  int tid = threadIdx.x;
  int lane = tid & 63, wid = tid >> 6;
  int wm = wid >> 1, wn = wid & 1;
  int quad = lane >> 4, l16 = lane & 15;

  // XCD-contiguous bijective swizzle (4096 blocks = 8 x 512)
  int bid = blockIdx.y * 32 + blockIdx.x;
  int swz = (bid & 7) * 512 + (bid >> 3);
  int bx = swz & 31, by = swz >> 5;
  int n0 = bx * 128;
  int part = bx & 3, hh = bx >> 2;
  int bb = by & 63, lhalf = by >> 6;

  const unsigned short* Ab = A + ((size_t)(lhalf * 128) * 64 + bb) * DM_;
  const size_t lda = (size_t)64 * DM_;
  const unsigned short* Bb = B + (size_t)n0 * DM_;

  floatx4 acc[4][4];
#pragma unroll
  for (int i = 0; i < 4; ++i)
#pragma unroll
    for (int j = 0; j < 4; ++j)
#pragma unroll
      for (int r = 0; r < 4; ++r) acc[i][j][r] = 0.f;

  for (int kt = 0; kt < DM_; kt += 64) {
    stage_async(Ab + kt, lda, As, tid);
    stage_async(Bb + kt, DM_, Bs, tid);
    __syncthreads();
#pragma unroll
    for (int kk = 0; kk < 2; ++kk) {
      short8 af[4], bfv[4];
#pragma unroll
      for (int mt = 0; mt < 4; ++mt)
        af[mt] = lds_frag(As, wm * 64 + mt * 16 + l16, kk * 4 + quad);
#pragma unroll
      for (int nt = 0; nt < 4; ++nt)
        bfv[nt] = lds_frag(Bs, wn * 64 + nt * 16 + l16, kk * 4 + quad);
#pragma unroll
      for (int mt = 0; mt < 4; ++mt)
#pragma unroll
        for (int nt = 0; nt < 4; ++nt)
          acc[mt][nt] = __builtin_amdgcn_mfma_f32_16x16x32_bf16(af[mt], bfv[nt], acc[mt][nt], 0, 0, 0);
    }
    __syncthreads();
  }

  int c = tid & 15, g = tid >> 4;
  if (part < 3) {
    // ---- phi: elu+1, row-sum across wave pair (wn=0/1 halves) ----
    float rsum[4][4];
#pragma unroll
    for (int mt = 0; mt < 4; ++mt)
#pragma unroll
      for (int r = 0; r < 4; ++r) rsum[mt][r] = 0.f;
#pragma unroll
    for (int mt = 0; mt < 4; ++mt)
#pragma unroll
      for (int nt = 0; nt < 4; ++nt)
#pragma unroll
        for (int r = 0; r < 4; ++r) {
          float x = acc[mt][nt][r];
          float f = x > 0.f ? x + 1.f : __expf(x);
          acc[mt][nt][r] = f;
          rsum[mt][r] += f;
        }
#pragma unroll
    for (int off = 1; off < 16; off <<= 1)
#pragma unroll
      for (int mt = 0; mt < 4; ++mt)
#pragma unroll
        for (int r = 0; r < 4; ++r)
          rsum[mt][r] += __shfl_xor(rsum[mt][r], off);
    float* Pf = (float*)Sh;              // [128][2] partials = 1KB
    if (l16 == 0) {
#pragma unroll
      for (int mt = 0; mt < 4; ++mt)
#pragma unroll
        for (int r = 0; r < 4; ++r)
          Pf[(wm * 64 + mt * 16 + quad * 4 + r) * 2 + wn] = rsum[mt][r];
    }
    __syncthreads();
    float inv[4][4];
#pragma unroll
    for (int mt = 0; mt < 4; ++mt)
#pragma unroll
      for (int r = 0; r < 4; ++r)
        inv[mt][r] = 1.f / (rsum[mt][r] + Pf[(wm * 64 + mt * 16 + quad * 4 + r) * 2 + (wn ^ 1)]);
    __syncthreads();
    // stage normalized P in T[128][136]
#pragma unroll
    for (int mt = 0; mt < 4; ++mt)
#pragma unroll
      for (int nt = 0; nt < 4; ++nt)
#pragma unroll
        for (int r = 0; r < 4; ++r) {
          int row = wm * 64 + mt * 16 + quad * 4 + r;
          int col = wn * 64 + nt * 16 + l16;
          Sh[row * 136 + col] = f2b(acc[mt][nt][r] * inv[mt][r]);
        }
    __syncthreads();
    unsigned short* P = QKV + (size_t)part * 16777216 + (size_t)(bb * 8 + hh) * 32768
                            + (size_t)(lhalf * 128) * 128;
#pragma unroll
    for (int j = 0; j < 8; ++j) {
      int row = j * 16 + g;
      *(short8*)(P + (size_t)row * 128 + c * 8) = *(const short8*)(Sh + row * 136 + c * 8);
    }
  } else {
    // ---- V: transpose-stage T[d][l] then full-line Vt stores ----
#pragma unroll
    for (int mt = 0; mt < 4; ++mt)
#pragma unroll
      for (int nt = 0; nt < 4; ++nt)
#pragma unroll
        for (int r = 0; r < 4; ++r) {
          int l = wm * 64 + mt * 16 + quad * 4 + r;
          int d = wn * 64 + nt * 16 + l16;
          Sh[d * 136 + l] = f2b(acc[mt][nt][r]);
        }
    __syncthreads();
    unsigned short* Vt = QKV + (size_t)3 * 16777216 + (size_t)(bb * 8 + hh) * 32768;
#pragma unroll
    for (int j = 0; j < 8; ++j) {
      int d = j * 16 + g;
      *(short8*)(Vt + (size_t)d * 256 + lhalf * 128 + c * 8) = *(const short8*)(Sh + d * 136 + c * 8);
    }
  }
}

// =====================================================================
// K3: combined masked scores.  grid (3, 1, 512); full-line S stores.
// =====================================================================
__global__ __launch_bounds__(256) void scores_kernel(const unsigned short* __restrict__ QKV,
                                                     const float* __restrict__ pi0,
                                                     unsigned short* __restrict__ S) {
  __shared__ alignas(16) unsigned short Sh[24576];   // As|Bs1|Bs2; reused as T[128][136]
  __shared__ float pis[128];
  unsigned short* As  = Sh;
  unsigned short* Bs1 = Sh + 8192;
  unsigned short* Bs2 = Sh + 16384;
  int p = blockIdx.z;
  int hh = p & 7;
  int tid = threadIdx.x;
  int lane = tid & 63, wid = tid >> 6;
  int wm = wid >> 1, wn = wid & 1;
  int quad = lane >> 4, l16 = lane & 15;
  int tix = blockIdx.x;
  int m0 = (tix >= 1) ? 128 : 0;
  int n0 = (tix == 2) ? 128 : 0;
  if (tid < 128) {
    float pv = pi0[hh * 256 + m0 + tid];
    pis[tid] = fminf(fmaxf(pv, 0.f), 1.f);
  }
  const unsigned short* Qb  = QKV + (size_t)p * 32768 + (size_t)m0 * 128;
  const unsigned short* K1b = QKV + 16777216     + (size_t)p * 32768 + (size_t)n0 * 128;
  const unsigned short* K2b = QKV + 2 * 16777216 + (size_t)p * 32768 + (size_t)n0 * 128;

  floatx4 acc1[4][4], acc2[4][4];
#pragma unroll
  for (int i = 0; i < 4; ++i)
#pragma unroll
    for (int j = 0; j < 4; ++j)
#pragma unroll
      for (int r = 0; r < 4; ++r) { acc1[i][j][r] = 0.f; acc2[i][j][r] = 0.f; }

  for (int kt = 0; kt < 128; kt += 64) {
    stage_async(Qb + kt, 128, As, tid);
    stage_async(K1b + kt, 128, Bs1, tid);
    stage_async(K2b + kt, 128, Bs2, tid);
    __syncthreads();
#pragma unroll
    for (int kk = 0; kk < 2; ++kk) {
      short8 af[4], b1[4], b2v[4];
#pragma unroll
      for (int mt = 0; mt < 4; ++mt)
        af[mt] = lds_frag(As, wm * 64 + mt * 16 + l16, kk * 4 + quad);
#pragma unroll
      for (int nt = 0; nt < 4; ++nt) {
        b1[nt]  = lds_frag(Bs1, wn * 64 + nt * 16 + l16, kk * 4 + quad);
        b2v[nt] = lds_frag(Bs2, wn * 64 + nt * 16 + l16, kk * 4 + quad);
      }
#pragma unroll
      for (int mt = 0; mt < 4; ++mt)
#pragma unroll
        for (int nt = 0; nt < 4; ++nt) {
          acc1[mt][nt] = __builtin_amdgcn_mfma_f32_16x16x32_bf16(af[mt], b1[nt],  acc1[mt][nt], 0, 0, 0);
          acc2[mt][nt] = __builtin_amdgcn_mfma_f32_16x16x32_bf16(af[mt], b2v[nt], acc2[mt][nt], 0, 0, 0);
        }
    }
    __syncthreads();
  }
  // combine + mask -> T[128][136]
#pragma unroll
  for (int mt = 0; mt < 4; ++mt)
#pragma unroll
    for (int nt = 0; nt < 4; ++nt)
#pragma unroll
      for (int r = 0; r < 4; ++r) {
        int tl = wm * 64 + mt * 16 + quad * 4 + r;
        int sl = wn * 64 + nt * 16 + l16;
        float pv = pis[tl];
        float v = (n0 + sl <= m0 + tl) ? (pv * acc1[mt][nt][r] + (1.f - pv) * acc2[mt][nt][r]) : 0.f;
        Sh[tl * 136 + sl] = f2b(v);
      }
  __syncthreads();
  int c = tid & 15, g = tid >> 4;
#pragma unroll
  for (int j = 0; j < 8; ++j) {
    int r = j * 16 + g;
    size_t gb = (size_t)p * 65536 + (size_t)(m0 + r) * 256 + n0 + c * 8;
    *(short8*)(S + gb) = *(const short8*)(Sh + r * 136 + c * 8);
  }
}

// =====================================================================
// K4: O = SCALE * S @ V -> LO; full-line stores.  grid (1,2,512)
// =====================================================================
__global__ __launch_bounds__(256, 4) void pv_kernel(const unsigned short* __restrict__ S,
                                                    const unsigned short* __restrict__ Vt,
                                                    unsigned short* __restrict__ LO) {
  __shared__ alignas(16) unsigned short Sh[17408];   // As|Bs; reused as T[128][136]
  unsigned short* As = Sh;
  unsigned short* Bs = Sh + 8192;
  int p = blockIdx.z;
  int b = p >> 3, hh = p & 7;
  int tid = threadIdx.x;
  int lane = tid & 63, wid = tid >> 6;
  int wm = wid >> 1, wn = wid & 1;
  int quad = lane >> 4, l16 = lane & 15;
  int m0 = blockIdx.y * 128;
  int kEnd = (blockIdx.y == 0) ? 128 : 256;   // rows t<128 only need s<128
  const unsigned short* Ab = S  + (size_t)p * 65536 + (size_t)m0 * 256;
  const unsigned short* Bb = Vt + (size_t)p * 32768;

  floatx4 acc[4][4];
#pragma unroll
  for (int i = 0; i < 4; ++i)
#pragma unroll
    for (int j = 0; j < 4; ++j)
#pragma unroll
      for (int r = 0; r < 4; ++r) acc[i][j][r] = 0.f;

  for (int kt = 0; kt < kEnd; kt += 64) {
    stage_async(Ab + kt, 256, As, tid);
    stage_async(Bb + kt, 256, Bs, tid);
    __syncthreads();
#pragma unroll
    for (int kk = 0; kk < 2; ++kk) {
      short8 af[4], bfv[4];
#pragma unroll
      for (int mt = 0; mt < 4; ++mt)
        af[mt] = lds_frag(As, wm * 64 + mt * 16 + l16, kk * 4 + quad);
#pragma unroll
      for (int nt = 0; nt < 4; ++nt)
        bfv[nt] = lds_frag(Bs, wn * 64 + nt * 16 + l16, kk * 4 + quad);
#pragma unroll
      for (int mt = 0; mt < 4; ++mt)
#pragma unroll
        for (int nt = 0; nt < 4; ++nt)
          acc[mt][nt] = __builtin_amdgcn_mfma_f32_16x16x32_bf16(af[mt], bfv[nt], acc[mt][nt], 0, 0, 0);
    }
    __syncthreads();
  }
  // stage scaled O into T[128][136]
#pragma unroll
  for (int mt = 0; mt < 4; ++mt)
#pragma unroll
    for (int nt = 0; nt < 4; ++nt)
#pragma unroll
      for (int r = 0; r < 4; ++r) {
        int tl = wm * 64 + mt * 16 + quad * 4 + r;
        int d = wn * 64 + nt * 16 + l16;
        Sh[tl * 136 + d] = f2b(SCALE_ * acc[mt][nt][r]);
      }
  __syncthreads();
  int c = tid & 15, g = tid >> 4;
#pragma unroll
  for (int j = 0; j < 8; ++j) {
    int r = j * 16 + g;
    int t = m0 + r;
    size_t gb = ((size_t)t * 64 + b) * 1024 + hh * 128 + c * 8;
    *(short8*)(LO + gb) = *(const short8*)(Sh + r * 136 + c * 8);
  }
}

// =====================================================================
// K5: X[row,m] = h[row,m] + sum_n LO[row,n]*Wo[m,n]  (X fp32 = d_out)
// =====================================================================
__global__ __launch_bounds__(256, 4) void wo_gemm(const unsigned short* __restrict__ A,
                                                  const unsigned short* __restrict__ B,
                                                  const float* __restrict__ hin,
                                                  float* __restrict__ X) {
  __shared__ alignas(16) unsigned short As[128 * 64], Bs[128 * 64];
  int tid = threadIdx.x;
  int lane = tid & 63, wid = tid >> 6;
  int wm = wid >> 1, wn = wid & 1;
  int quad = lane >> 4, l16 = lane & 15;
  int m0 = blockIdx.y * 128, n0 = blockIdx.x * 128;
  const unsigned short* Ab = A + (size_t)m0 * DM_;
  const unsigned short* Bb = B + (size_t)n0 * DM_;

  floatx4 acc[4][4];
#pragma unroll
  for (int i = 0; i < 4; ++i)
#pragma unroll
    for (int j = 0; j < 4; ++j)
#pragma unroll
      for (int r = 0; r < 4; ++r) acc[i][j][r] = 0.f;

  for (int kt = 0; kt < DM_; kt += 64) {
    stage_async(Ab + kt, DM_, As, tid);
    stage_async(Bb + kt, DM_, Bs, tid);
    __syncthreads();
#pragma unroll
    for (int kk = 0; kk < 2; ++kk) {
      short8 af[4], bfv[4];
#pragma unroll
      for (int mt = 0; mt < 4; ++mt)
        af[mt] = lds_frag(As, wm * 64 + mt * 16 + l16, kk * 4 + quad);
#pragma unroll
      for (int nt = 0; nt < 4; ++nt)
        bfv[nt] = lds_frag(Bs, wn * 64 + nt * 16 + l16, kk * 4 + quad);
#pragma unroll
      for (int mt = 0; mt < 4; ++mt)
#pragma unroll
        for (int nt = 0; nt < 4; ++nt)
          acc[mt][nt] = __builtin_amdgcn_mfma_f32_16x16x32_bf16(af[mt], bfv[nt], acc[mt][nt], 0, 0, 0);
    }
    __syncthreads();
  }
#pragma unroll
  for (int mt = 0; mt < 4; ++mt)
#pragma unroll
    for (int nt = 0; nt < 4; ++nt)
#pragma unroll
      for (int r = 0; r < 4; ++r) {
        int row = m0 + wm * 64 + mt * 16 + quad * 4 + r;
        int col = n0 + wn * 64 + nt * 16 + l16;
        size_t idx = (size_t)row * DM_ + col;
        X[idx] = acc[mt][nt][r] + hin[idx];
      }
}

// =====================================================================
// K6: LayerNorm in-place on X (= d_out, fp32).  One block per row.
// =====================================================================
__global__ __launch_bounds__(256) void ln_kernel(float* __restrict__ X,
                                                 const float* __restrict__ gamma,
                                                 const float* __restrict__ beta) {
  int row = blockIdx.x;
  int tid = threadIdx.x;
  float* x = X + (size_t)row * DM_;
  float4 v = *(const float4*)(x + tid * 4);
  float s  = v.x + v.y + v.z + v.w;
  float ss = v.x * v.x + v.y * v.y + v.z * v.z + v.w * v.w;
#pragma unroll
  for (int off = 32; off; off >>= 1) {
    s  += __shfl_down(s, off);
    ss += __shfl_down(ss, off);
  }
  __shared__ float rs[4], rss[4];
  int wv = tid >> 6, lane = tid & 63;
  if (lane == 0) { rs[wv] = s; rss[wv] = ss; }
  __syncthreads();
  float St  = rs[0] + rs[1] + rs[2] + rs[3];
  float SSt = rss[0] + rss[1] + rss[2] + rss[3];
  float mu = St * (1.f / DM_);
  float var = SSt * (1.f / DM_) - mu * mu;
  float rstd = rsqrtf(var + LN_EPS_);
  float4 o;
#pragma unroll
  for (int j = 0; j < 4; ++j) {
    int c = tid * 4 + j;
    (&o.x)[j] = gamma[c] * ((&v.x)[j] - mu) * rstd + beta[c];
  }
  *(float4*)(x + tid * 4) = o;
}

// =====================================================================
extern "C" void kernel_launch(void* const* d_in, const int* in_sizes, int n_in,
                              void* d_out, int out_size, void* d_ws, size_t ws_size,
                              hipStream_t stream) {
  const float* h     = (const float*)d_in[0];
  const float* Wqkv  = (const float*)d_in[1];
  const float* Wo    = (const float*)d_in[2];
  const float* pi0   = (const float*)d_in[3];
  const float* gamma = (const float*)d_in[4];
  const float* beta  = (const float*)d_in[5];
  char* ws = (char*)d_ws;

  unsigned short* QKV   = (unsigned short*)ws;
  unsigned short* Sbuf  = (unsigned short*)(ws + 134217728ull);
  unsigned short* hb    = (unsigned short*)(ws + 134217728ull);
  unsigned short* Wqkvb = (unsigned short*)(ws + 167772160ull);
  unsigned short* Wob   = (unsigned short*)(ws + 201326592ull);
  unsigned short* LO    = (unsigned short*)ws;
  float* X = (float*)d_out;

  dim3 blk(256);
  cvt_all<<<dim3(10752), blk, 0, stream>>>(h, Wqkv, Wo, hb, Wqkvb, Wob);
  qkv_gemm<<<dim3(32, 128, 1), blk, 0, stream>>>(hb, Wqkvb, QKV);
  scores_kernel<<<dim3(3, 1, PAIRS_), blk, 0, stream>>>(QKV, pi0, Sbuf);
  pv_kernel<<<dim3(1, 2, PAIRS_), blk, 0, stream>>>(Sbuf, QKV + (size_t)3 * 16777216, LO);
  wo_gemm<<<dim3(DM_ / 128, ROWS_ / 128, 1), blk, 0, stream>>>(LO, Wob, h, X);
  ln_kernel<<<dim3(ROWS_, 1, 1), blk, 0, stream>>>(X, gamma, beta);
}

// Round 5
// 423.932 us; speedup vs baseline: 1.2161x; 1.2161x over previous
//
#include <hip/hip_runtime.h>

// ---- problem constants ----
#define H_     8
#define DM_    1024
#define NQKV_  4096
#define ROWS_  16384          // SLEN*BSZ = 256*64
#define PAIRS_ 512            // BSZ*H
#define SCALE_ 0.08838834764831845f
#define LN_EPS_ 1e-5f

typedef __attribute__((ext_vector_type(8))) short short8;   // 8 bf16 (4 VGPRs)
typedef __attribute__((ext_vector_type(4))) short short4v;  // 4 bf16
typedef __attribute__((ext_vector_type(4))) float floatx4;  // MFMA accumulator

__device__ __forceinline__ float b2f(unsigned short u) {
  union { unsigned int i; float f; } v; v.i = ((unsigned int)u) << 16; return v.f;
}
__device__ __forceinline__ unsigned short f2b(float f) {
  union { unsigned int i; float f; } v; v.f = f;
  unsigned int b = v.i;
  b += 0x7FFFu + ((b >> 16) & 1u);   // round-to-nearest-even
  return (unsigned short)(b >> 16);
}

// ---- async stage with XOR bank swizzle (256 threads, 128x64 tile) ----
__device__ __forceinline__ void stage_async(const unsigned short* __restrict__ g,
                                            size_t ld, unsigned short* s, int tid) {
#pragma unroll
  for (int p = 0; p < 4; ++p) {
    int idx = p * 256 + tid;
    int r = idx >> 3, j = idx & 7;
    int cg = j ^ (r & 7);
    __builtin_amdgcn_global_load_lds(
        (const __attribute__((address_space(1))) unsigned int*)(g + (size_t)r * ld + cg * 8),
        (__attribute__((address_space(3))) unsigned int*)(s + (size_t)idx * 8),
        16, 0, 0);
  }
}
// ---- 512-thread half-tile stage with precomputed per-lane offsets ----
__device__ __forceinline__ void stage_h(const unsigned short* __restrict__ g,
                                        size_t o0, size_t o1,
                                        unsigned short* s, int lo0, int lo1) {
  __builtin_amdgcn_global_load_lds(
      (const __attribute__((address_space(1))) unsigned int*)(g + o0),
      (__attribute__((address_space(3))) unsigned int*)(s + lo0), 16, 0, 0);
  __builtin_amdgcn_global_load_lds(
      (const __attribute__((address_space(1))) unsigned int*)(g + o1),
      (__attribute__((address_space(3))) unsigned int*)(s + lo1), 16, 0, 0);
}
__device__ __forceinline__ short8 lds_frag(const unsigned short* s, int row, int cg) {
  return *(const short8*)(s + row * 64 + ((cg ^ (row & 7)) << 3));
}

// =====================================================================
// K0: fused fp32 -> bf16 convert of h, Wqkv, Wo (8 elems/thread)
// =====================================================================
__global__ __launch_bounds__(256) void cvt_all(const float* __restrict__ h,
                                               const float* __restrict__ wq,
                                               const float* __restrict__ wo,
                                               unsigned short* __restrict__ hb,
                                               unsigned short* __restrict__ wqb,
                                               unsigned short* __restrict__ wob) {
  int i = blockIdx.x * 256 + threadIdx.x;
  const float* src; unsigned short* dst; int off;
  if (i < 2097152)      { src = h;  dst = hb;  off = i; }
  else if (i < 2621440) { src = wq; dst = wqb; off = i - 2097152; }
  else                  { src = wo; dst = wob; off = i - 2621440; }
  const float4* s4 = (const float4*)(src + (size_t)off * 8);
  float4 v0 = s4[0], v1 = s4[1];
  union { short8 v; unsigned short u[8]; } pk;
  pk.u[0] = f2b(v0.x); pk.u[1] = f2b(v0.y); pk.u[2] = f2b(v0.z); pk.u[3] = f2b(v0.w);
  pk.u[4] = f2b(v1.x); pk.u[5] = f2b(v1.y); pk.u[6] = f2b(v1.z); pk.u[7] = f2b(v1.w);
  *(short8*)(dst + (size_t)off * 8) = pk.v;
}

// =====================================================================
// Shared 256x256 4-phase K-loop macro (proven in qkv: 174 us, ~790 TF).
//   Requires in scope: acc[8][4], wm, wn, quad, l16, s7, lo0, lo1,
//   AbP, AbHP, BbP, BbHP (tile base ptrs), oA0,oA1,oB0,oB1.
// =====================================================================
#define TILE_BODY(T, BUF, OBUF)                                                \
  {                                                                            \
    unsigned short* SB = (BUF) + 16384;                                        \
    const unsigned short* aA0 = (BUF) + (wm * 128 + l16) * 64 + ((quad ^ s7) << 3); \
    const unsigned short* aA1 = (BUF) + (wm * 128 + l16) * 64 + (((4 + quad) ^ s7) << 3); \
    const unsigned short* bA0 = SB + (wn * 64 + l16) * 64 + ((quad ^ s7) << 3);\
    const unsigned short* bA1 = SB + (wn * 64 + l16) * 64 + (((4 + quad) ^ s7) << 3); \
    short8 a[8], b[4];                                                         \
    /* ---- P1: stage B(T+1) -> OBUF; read a0(8) + b0(4) ---- */               \
    if ((T) < 15) {                                                            \
      size_t kn = (size_t)((T) + 1) * 64;                                      \
      stage_h(BbP + kn,  oB0, oB1, (OBUF) + 16384, lo0, lo1);                  \
      stage_h(BbHP + kn, oB0, oB1, (OBUF) + 24576, lo0, lo1);                  \
    }                                                                          \
    _Pragma("unroll")                                                          \
    for (int mt = 0; mt < 4; ++mt) {                                           \
      a[mt * 2 + 0] = *(const short8*)(aA0 + mt * 1024);                       \
      a[mt * 2 + 1] = *(const short8*)(aA1 + mt * 1024);                       \
    }                                                                          \
    _Pragma("unroll")                                                          \
    for (int nt = 0; nt < 2; ++nt) {                                           \
      b[nt * 2 + 0] = *(const short8*)(bA0 + nt * 1024);                       \
      b[nt * 2 + 1] = *(const short8*)(bA1 + nt * 1024);                       \
    }                                                                          \
    __builtin_amdgcn_sched_barrier(0);                                         \
    __builtin_amdgcn_s_barrier();                                              \
    __builtin_amdgcn_s_setprio(1);                                             \
    _Pragma("unroll")                                                          \
    for (int kk = 0; kk < 2; ++kk)                                             \
      _Pragma("unroll")                                                        \
      for (int m = 0; m < 4; ++m)                                              \
        _Pragma("unroll")                                                      \
        for (int n = 0; n < 2; ++n)                                            \
          acc[m][n] = __builtin_amdgcn_mfma_f32_16x16x32_bf16(a[m * 2 + kk], b[n * 2 + kk], acc[m][n], 0, 0, 0); \
    __builtin_amdgcn_s_setprio(0);                                             \
    __builtin_amdgcn_s_barrier();                                              \
    /* ---- P2: read b1(4) ---- */                                             \
    _Pragma("unroll")                                                          \
    for (int nt = 0; nt < 2; ++nt) {                                           \
      b[nt * 2 + 0] = *(const short8*)(bA0 + 2048 + nt * 1024);                \
      b[nt * 2 + 1] = *(const short8*)(bA1 + 2048 + nt * 1024);                \
    }                                                                          \
    __builtin_amdgcn_sched_barrier(0);                                         \
    __builtin_amdgcn_s_barrier();                                              \
    __builtin_amdgcn_s_setprio(1);                                             \
    _Pragma("unroll")                                                          \
    for (int kk = 0; kk < 2; ++kk)                                             \
      _Pragma("unroll")                                                        \
      for (int m = 0; m < 4; ++m)                                              \
        _Pragma("unroll")                                                      \
        for (int n = 0; n < 2; ++n)                                            \
          acc[m][2 + n] = __builtin_amdgcn_mfma_f32_16x16x32_bf16(a[m * 2 + kk], b[n * 2 + kk], acc[m][2 + n], 0, 0, 0); \
    __builtin_amdgcn_s_setprio(0);                                             \
    __builtin_amdgcn_s_barrier();                                              \
    /* ---- P3: read a1(8), reuse b1 ---- */                                   \
    _Pragma("unroll")                                                          \
    for (int mt = 0; mt < 4; ++mt) {                                           \
      a[mt * 2 + 0] = *(const short8*)(aA0 + 4096 + mt * 1024);                \
      a[mt * 2 + 1] = *(const short8*)(aA1 + 4096 + mt * 1024);                \
    }                                                                          \
    __builtin_amdgcn_sched_barrier(0);                                         \
    __builtin_amdgcn_s_barrier();                                              \
    __builtin_amdgcn_s_setprio(1);                                             \
    _Pragma("unroll")                                                          \
    for (int kk = 0; kk < 2; ++kk)                                             \
      _Pragma("unroll")                                                        \
      for (int m = 0; m < 4; ++m)                                              \
        _Pragma("unroll")                                                      \
        for (int n = 0; n < 2; ++n)                                            \
          acc[4 + m][2 + n] = __builtin_amdgcn_mfma_f32_16x16x32_bf16(a[m * 2 + kk], b[n * 2 + kk], acc[4 + m][2 + n], 0, 0, 0); \
    __builtin_amdgcn_s_setprio(0);                                             \
    __builtin_amdgcn_s_barrier();                                              \
    /* ---- P4: stage A(T+2) -> own A region; re-read b0(4) ---- */            \
    if ((T) < 14) {                                                            \
      size_t kt2 = (size_t)((T) + 2) * 64;                                     \
      stage_h(AbP + kt2,  oA0, oA1, (BUF),        lo0, lo1);                   \
      stage_h(AbHP + kt2, oA0, oA1, (BUF) + 8192, lo0, lo1);                   \
    }                                                                          \
    _Pragma("unroll")                                                          \
    for (int nt = 0; nt < 2; ++nt) {                                           \
      b[nt * 2 + 0] = *(const short8*)(bA0 + nt * 1024);                       \
      b[nt * 2 + 1] = *(const short8*)(bA1 + nt * 1024);                       \
    }                                                                          \
    __builtin_amdgcn_sched_barrier(0);                                         \
    __builtin_amdgcn_s_barrier();                                              \
    __builtin_amdgcn_s_setprio(1);                                             \
    _Pragma("unroll")                                                          \
    for (int kk = 0; kk < 2; ++kk)                                             \
      _Pragma("unroll")                                                        \
      for (int m = 0; m < 4; ++m)                                              \
        _Pragma("unroll")                                                      \
        for (int n = 0; n < 2; ++n)                                            \
          acc[4 + m][n] = __builtin_amdgcn_mfma_f32_16x16x32_bf16(a[m * 2 + kk], b[n * 2 + kk], acc[4 + m][n], 0, 0, 0); \
    __builtin_amdgcn_s_setprio(0);                                             \
    if ((T) < 14) { asm volatile("s_waitcnt vmcnt(4)" ::: "memory"); }         \
    else          { asm volatile("s_waitcnt vmcnt(0)" ::: "memory"); }         \
    __builtin_amdgcn_s_barrier();                                              \
  }

// =====================================================================
// K1: qkv gemm, 256x256 tile, gray-code 4-phase schedule (round-2 best).
// =====================================================================
__global__ __launch_bounds__(512, 1) void qkv_gemm(const unsigned short* __restrict__ A,
                                                   const unsigned short* __restrict__ B,
                                                   unsigned short* __restrict__ QKV) {
  __shared__ alignas(16) unsigned short Sh[65536];
  int tid = threadIdx.x;
  int lane = tid & 63, wid = tid >> 6;
  int wm = wid >> 2, wn = wid & 3;          // 2M x 4N wave grid
  int quad = lane >> 4, l16 = lane & 15;
  int s7 = l16 & 7;

  // XCD-contiguous block swizzle (1024 blocks, bijective: 8 x 128)
  int bid = blockIdx.y * 16 + blockIdx.x;
  int swz = (bid & 7) * 128 + (bid >> 3);
  int bx = swz & 15, by = swz >> 4;
  int n0 = bx * 256, hh = bx >> 1, part0 = (bx & 1) * 2, bb = by;

  const unsigned short* AbP = A + (size_t)bb * DM_;   // row l at AbP + l*lda
  const size_t lda = (size_t)64 * DM_;
  const unsigned short* AbHP = AbP + (size_t)128 * lda;
  const unsigned short* BbP = B + (size_t)n0 * DM_;
  const unsigned short* BbHP = BbP + (size_t)128 * DM_;

  int r0 = tid >> 3, jj = tid & 7;
  int cg = jj ^ (r0 & 7);
  size_t oA0 = (size_t)r0 * lda + cg * 8;
  size_t oA1 = (size_t)(r0 + 64) * lda + cg * 8;
  size_t oB0 = (size_t)r0 * DM_ + cg * 8;
  size_t oB1 = (size_t)(r0 + 64) * DM_ + cg * 8;
  int lo0 = tid * 8, lo1 = 4096 + tid * 8;

  floatx4 acc[8][4];
#pragma unroll
  for (int i = 0; i < 8; ++i)
#pragma unroll
    for (int j = 0; j < 4; ++j)
#pragma unroll
      for (int r = 0; r < 4; ++r) acc[i][j][r] = 0.f;

  stage_h(AbP,        oA0, oA1, Sh,         lo0, lo1);
  stage_h(AbHP,       oA0, oA1, Sh + 8192,  lo0, lo1);
  stage_h(BbP,        oB0, oB1, Sh + 16384, lo0, lo1);
  stage_h(BbHP,       oB0, oB1, Sh + 24576, lo0, lo1);
  stage_h(AbP + 64,   oA0, oA1, Sh + 32768, lo0, lo1);
  stage_h(AbHP + 64,  oA0, oA1, Sh + 40960, lo0, lo1);
  asm volatile("s_waitcnt vmcnt(4)" ::: "memory");
  __builtin_amdgcn_s_barrier();

  for (int t = 0; t < 16; t += 2) {
    TILE_BODY(t,     Sh,         Sh + 32768)
    TILE_BODY(t + 1, Sh + 32768, Sh)
  }

  // ================= epilogue =================
  __syncthreads();
  bool isV = (part0 + (wn >> 1)) == 3;
  float* Pf = (float*)Sh;                 // partial row-sums [256][4] floats
  float rsum[8][4];
  float inv[8][4];
  if (!isV) {
#pragma unroll
    for (int mt = 0; mt < 8; ++mt)
#pragma unroll
      for (int r = 0; r < 4; ++r) rsum[mt][r] = 0.f;
#pragma unroll
    for (int mt = 0; mt < 8; ++mt)
#pragma unroll
      for (int nt = 0; nt < 4; ++nt)
#pragma unroll
        for (int r = 0; r < 4; ++r) {
          float x = acc[mt][nt][r];
          float f = x > 0.f ? x + 1.f : __expf(x);
          acc[mt][nt][r] = f;
          rsum[mt][r] += f;
        }
#pragma unroll
    for (int off = 1; off < 16; off <<= 1)
#pragma unroll
      for (int mt = 0; mt < 8; ++mt)
#pragma unroll
        for (int r = 0; r < 4; ++r)
          rsum[mt][r] += __shfl_xor(rsum[mt][r], off);
    if (l16 == 0) {
#pragma unroll
      for (int mt = 0; mt < 8; ++mt)
#pragma unroll
        for (int r = 0; r < 4; ++r)
          Pf[(wm * 128 + mt * 16 + quad * 4 + r) * 4 + wn] = rsum[mt][r];
    }
  }
  __syncthreads();
  if (!isV) {
#pragma unroll
    for (int mt = 0; mt < 8; ++mt)
#pragma unroll
      for (int r = 0; r < 4; ++r)
        inv[mt][r] = 1.f / (rsum[mt][r] + Pf[(wm * 128 + mt * 16 + quad * 4 + r) * 4 + (wn ^ 1)]);
  }
  __syncthreads();

#pragma unroll
  for (int hq = 0; hq < 2; ++hq) {
    int part = part0 + hq;
    if ((wn >> 1) == hq) {
      if (part < 3) {
#pragma unroll
        for (int mt = 0; mt < 8; ++mt)
#pragma unroll
          for (int nt = 0; nt < 4; ++nt)
#pragma unroll
            for (int r = 0; r < 4; ++r) {
              int row = wm * 128 + mt * 16 + quad * 4 + r;
              int col = (wn & 1) * 64 + nt * 16 + l16;
              Sh[row * 136 + col] = f2b(acc[mt][nt][r] * inv[mt][r]);
            }
      } else {
#pragma unroll
        for (int mt = 0; mt < 8; ++mt)
#pragma unroll
          for (int nt = 0; nt < 4; ++nt)
#pragma unroll
            for (int r = 0; r < 4; ++r) {
              int d = (wn & 1) * 64 + nt * 16 + l16;
              int l = wm * 128 + mt * 16 + quad * 4 + r;
              Sh[d * 264 + l] = f2b(acc[mt][nt][r]);
            }
      }
    }
    __syncthreads();
    if (part < 3) {
      unsigned short* P = QKV + (size_t)part * 16777216 + (size_t)(bb * 8 + hh) * 32768;
      int c = tid & 15, g = tid >> 4;
#pragma unroll
      for (int j = 0; j < 8; ++j) {
        int row = j * 32 + g;
        *(short8*)(P + (size_t)row * 128 + c * 8) = *(const short8*)(Sh + row * 136 + c * 8);
      }
    } else {
      unsigned short* Vt = QKV + (size_t)3 * 16777216 + (size_t)(bb * 8 + hh) * 32768;
      int cg2 = tid & 31, g = tid >> 5;
#pragma unroll
      for (int j = 0; j < 8; ++j) {
        int d = j * 16 + g;
        *(short8*)(Vt + (size_t)d * 256 + cg2 * 8) = *(const short8*)(Sh + d * 264 + cg2 * 8);
      }
    }
    __syncthreads();
  }
}

// =====================================================================
// K3: combined masked scores.  grid (3, 1, 512); full-line S stores.
// =====================================================================
__global__ __launch_bounds__(256) void scores_kernel(const unsigned short* __restrict__ QKV,
                                                     const float* __restrict__ pi0,
                                                     unsigned short* __restrict__ S) {
  __shared__ alignas(16) unsigned short Sh[24576];
  __shared__ float pis[128];
  unsigned short* As  = Sh;
  unsigned short* Bs1 = Sh + 8192;
  unsigned short* Bs2 = Sh + 16384;
  int p = blockIdx.z;
  int hh = p & 7;
  int tid = threadIdx.x;
  int lane = tid & 63, wid = tid >> 6;
  int wm = wid >> 1, wn = wid & 1;
  int quad = lane >> 4, l16 = lane & 15;
  int tix = blockIdx.x;
  int m0 = (tix >= 1) ? 128 : 0;
  int n0 = (tix == 2) ? 128 : 0;
  if (tid < 128) {
    float pv = pi0[hh * 256 + m0 + tid];
    pis[tid] = fminf(fmaxf(pv, 0.f), 1.f);
  }
  const unsigned short* Qb  = QKV + (size_t)p * 32768 + (size_t)m0 * 128;
  const unsigned short* K1b = QKV + 16777216     + (size_t)p * 32768 + (size_t)n0 * 128;
  const unsigned short* K2b = QKV + 2 * 16777216 + (size_t)p * 32768 + (size_t)n0 * 128;

  floatx4 acc1[4][4], acc2[4][4];
#pragma unroll
  for (int i = 0; i < 4; ++i)
#pragma unroll
    for (int j = 0; j < 4; ++j)
#pragma unroll
      for (int r = 0; r < 4; ++r) { acc1[i][j][r] = 0.f; acc2[i][j][r] = 0.f; }

  for (int kt = 0; kt < 128; kt += 64) {
    stage_async(Qb + kt, 128, As, tid);
    stage_async(K1b + kt, 128, Bs1, tid);
    stage_async(K2b + kt, 128, Bs2, tid);
    __syncthreads();
#pragma unroll
    for (int kk = 0; kk < 2; ++kk) {
      short8 af[4], b1[4], b2v[4];
#pragma unroll
      for (int mt = 0; mt < 4; ++mt)
        af[mt] = lds_frag(As, wm * 64 + mt * 16 + l16, kk * 4 + quad);
#pragma unroll
      for (int nt = 0; nt < 4; ++nt) {
        b1[nt]  = lds_frag(Bs1, wn * 64 + nt * 16 + l16, kk * 4 + quad);
        b2v[nt] = lds_frag(Bs2, wn * 64 + nt * 16 + l16, kk * 4 + quad);
      }
#pragma unroll
      for (int mt = 0; mt < 4; ++mt)
#pragma unroll
        for (int nt = 0; nt < 4; ++nt) {
          acc1[mt][nt] = __builtin_amdgcn_mfma_f32_16x16x32_bf16(af[mt], b1[nt],  acc1[mt][nt], 0, 0, 0);
          acc2[mt][nt] = __builtin_amdgcn_mfma_f32_16x16x32_bf16(af[mt], b2v[nt], acc2[mt][nt], 0, 0, 0);
        }
    }
    __syncthreads();
  }
#pragma unroll
  for (int mt = 0; mt < 4; ++mt)
#pragma unroll
    for (int nt = 0; nt < 4; ++nt)
#pragma unroll
      for (int r = 0; r < 4; ++r) {
        int tl = wm * 64 + mt * 16 + quad * 4 + r;
        int sl = wn * 64 + nt * 16 + l16;
        float pv = pis[tl];
        float v = (n0 + sl <= m0 + tl) ? (pv * acc1[mt][nt][r] + (1.f - pv) * acc2[mt][nt][r]) : 0.f;
        Sh[tl * 136 + sl] = f2b(v);
      }
  __syncthreads();
  int c = tid & 15, g = tid >> 4;
#pragma unroll
  for (int j = 0; j < 8; ++j) {
    int r = j * 16 + g;
    size_t gb = (size_t)p * 65536 + (size_t)(m0 + r) * 256 + n0 + c * 8;
    *(short8*)(S + gb) = *(const short8*)(Sh + r * 136 + c * 8);
  }
}

// =====================================================================
// K4: O = SCALE * S @ V -> LO; full-line stores.  grid (1,2,512)
// =====================================================================
__global__ __launch_bounds__(256, 4) void pv_kernel(const unsigned short* __restrict__ S,
                                                    const unsigned short* __restrict__ Vt,
                                                    unsigned short* __restrict__ LO) {
  __shared__ alignas(16) unsigned short Sh[17408];
  unsigned short* As = Sh;
  unsigned short* Bs = Sh + 8192;
  int p = blockIdx.z;
  int b = p >> 3, hh = p & 7;
  int tid = threadIdx.x;
  int lane = tid & 63, wid = tid >> 6;
  int wm = wid >> 1, wn = wid & 1;
  int quad = lane >> 4, l16 = lane & 15;
  int m0 = blockIdx.y * 128;
  int kEnd = (blockIdx.y == 0) ? 128 : 256;
  const unsigned short* Ab = S  + (size_t)p * 65536 + (size_t)m0 * 256;
  const unsigned short* Bb = Vt + (size_t)p * 32768;

  floatx4 acc[4][4];
#pragma unroll
  for (int i = 0; i < 4; ++i)
#pragma unroll
    for (int j = 0; j < 4; ++j)
#pragma unroll
      for (int r = 0; r < 4; ++r) acc[i][j][r] = 0.f;

  for (int kt = 0; kt < kEnd; kt += 64) {
    stage_async(Ab + kt, 256, As, tid);
    stage_async(Bb + kt, 256, Bs, tid);
    __syncthreads();
#pragma unroll
    for (int kk = 0; kk < 2; ++kk) {
      short8 af[4], bfv[4];
#pragma unroll
      for (int mt = 0; mt < 4; ++mt)
        af[mt] = lds_frag(As, wm * 64 + mt * 16 + l16, kk * 4 + quad);
#pragma unroll
      for (int nt = 0; nt < 4; ++nt)
        bfv[nt] = lds_frag(Bs, wn * 64 + nt * 16 + l16, kk * 4 + quad);
#pragma unroll
      for (int mt = 0; mt < 4; ++mt)
#pragma unroll
        for (int nt = 0; nt < 4; ++nt)
          acc[mt][nt] = __builtin_amdgcn_mfma_f32_16x16x32_bf16(af[mt], bfv[nt], acc[mt][nt], 0, 0, 0);
    }
    __syncthreads();
  }
#pragma unroll
  for (int mt = 0; mt < 4; ++mt)
#pragma unroll
    for (int nt = 0; nt < 4; ++nt)
#pragma unroll
      for (int r = 0; r < 4; ++r) {
        int tl = wm * 64 + mt * 16 + quad * 4 + r;
        int d = wn * 64 + nt * 16 + l16;
        Sh[tl * 136 + d] = f2b(SCALE_ * acc[mt][nt][r]);
      }
  __syncthreads();
  int c = tid & 15, g = tid >> 4;
#pragma unroll
  for (int j = 0; j < 8; ++j) {
    int r = j * 16 + g;
    int t = m0 + r;
    size_t gb = ((size_t)t * 64 + b) * 1024 + hh * 128 + c * 8;
    *(short8*)(LO + gb) = *(const short8*)(Sh + r * 136 + c * 8);
  }
}

// =====================================================================
// K5: attn_out = LO @ Wo^T (bf16 out, no residual) — 256x256 4-phase,
//     grid (4,64) = 256 blocks = 1/CU, single round.  Residual+LN moved
//     to K6 (drops hin read here, halves the output write size).
// =====================================================================
__global__ __launch_bounds__(512, 1) void wo_gemm(const unsigned short* __restrict__ A,
                                                  const unsigned short* __restrict__ B,
                                                  unsigned short* __restrict__ attn) {
  __shared__ alignas(16) unsigned short Sh[65536];
  int tid = threadIdx.x;
  int lane = tid & 63, wid = tid >> 6;
  int wm = wid >> 2, wn = wid & 3;
  int quad = lane >> 4, l16 = lane & 15;
  int s7 = l16 & 7;

  // 256 blocks, bijective XCD swizzle 8 x 32
  int bid = blockIdx.y * 4 + blockIdx.x;
  int swz = (bid & 7) * 32 + (bid >> 3);
  int bx = swz & 3, by = swz >> 2;
  int n0 = bx * 256, m0 = by * 256;

  const unsigned short* AbP = A + (size_t)m0 * DM_;
  const unsigned short* AbHP = AbP + (size_t)128 * DM_;
  const unsigned short* BbP = B + (size_t)n0 * DM_;
  const unsigned short* BbHP = BbP + (size_t)128 * DM_;

  int r0 = tid >> 3, jj = tid & 7;
  int cg = jj ^ (r0 & 7);
  size_t oA0 = (size_t)r0 * DM_ + cg * 8;
  size_t oA1 = (size_t)(r0 + 64) * DM_ + cg * 8;
  size_t oB0 = oA0, oB1 = oA1;
  int lo0 = tid * 8, lo1 = 4096 + tid * 8;

  floatx4 acc[8][4];
#pragma unroll
  for (int i = 0; i < 8; ++i)
#pragma unroll
    for (int j = 0; j < 4; ++j)
#pragma unroll
      for (int r = 0; r < 4; ++r) acc[i][j][r] = 0.f;

  stage_h(AbP,        oA0, oA1, Sh,         lo0, lo1);
  stage_h(AbHP,       oA0, oA1, Sh + 8192,  lo0, lo1);
  stage_h(BbP,        oB0, oB1, Sh + 16384, lo0, lo1);
  stage_h(BbHP,       oB0, oB1, Sh + 24576, lo0, lo1);
  stage_h(AbP + 64,   oA0, oA1, Sh + 32768, lo0, lo1);
  stage_h(AbHP + 64,  oA0, oA1, Sh + 40960, lo0, lo1);
  asm volatile("s_waitcnt vmcnt(4)" ::: "memory");
  __builtin_amdgcn_s_barrier();

  for (int t = 0; t < 16; t += 2) {
    TILE_BODY(t,     Sh,         Sh + 32768)
    TILE_BODY(t + 1, Sh + 32768, Sh)
  }

  // epilogue: bf16 stores via T[256][136], two 128-col halves
  __syncthreads();
#pragma unroll
  for (int hq = 0; hq < 2; ++hq) {
    if ((wn >> 1) == hq) {
#pragma unroll
      for (int mt = 0; mt < 8; ++mt)
#pragma unroll
        for (int nt = 0; nt < 4; ++nt)
#pragma unroll
          for (int r = 0; r < 4; ++r) {
            int row = wm * 128 + mt * 16 + quad * 4 + r;
            int col = (wn & 1) * 64 + nt * 16 + l16;
            Sh[row * 136 + col] = f2b(acc[mt][nt][r]);
          }
    }
    __syncthreads();
    int c = tid & 15, g = tid >> 4;
#pragma unroll
    for (int j = 0; j < 8; ++j) {
      int row = j * 32 + g;
      *(short8*)(attn + (size_t)(m0 + row) * DM_ + n0 + hq * 128 + c * 8) =
          *(const short8*)(Sh + row * 136 + c * 8);
    }
    __syncthreads();
  }
}

// =====================================================================
// K6: fused residual + LayerNorm: out = LN(h + attn_bf16).  1 block/row.
// =====================================================================
__global__ __launch_bounds__(256) void ln_res(const unsigned short* __restrict__ attn,
                                              const float* __restrict__ hin,
                                              const float* __restrict__ gamma,
                                              const float* __restrict__ beta,
                                              float* __restrict__ out) {
  int row = blockIdx.x;
  int tid = threadIdx.x;
  const unsigned short* ap = attn + (size_t)row * DM_ + tid * 4;
  const float* hp = hin + (size_t)row * DM_ + tid * 4;
  short4v av = *(const short4v*)ap;
  float4 hv = *(const float4*)hp;
  float x[4];
  x[0] = hv.x + b2f((unsigned short)av[0]);
  x[1] = hv.y + b2f((unsigned short)av[1]);
  x[2] = hv.z + b2f((unsigned short)av[2]);
  x[3] = hv.w + b2f((unsigned short)av[3]);
  float s  = x[0] + x[1] + x[2] + x[3];
  float ss = x[0] * x[0] + x[1] * x[1] + x[2] * x[2] + x[3] * x[3];
#pragma unroll
  for (int off = 32; off; off >>= 1) {
    s  += __shfl_down(s, off);
    ss += __shfl_down(ss, off);
  }
  __shared__ float rs[4], rss[4];
  int wv = tid >> 6, lane = tid & 63;
  if (lane == 0) { rs[wv] = s; rss[wv] = ss; }
  __syncthreads();
  float St  = rs[0] + rs[1] + rs[2] + rs[3];
  float SSt = rss[0] + rss[1] + rss[2] + rss[3];
  float mu = St * (1.f / DM_);
  float var = SSt * (1.f / DM_) - mu * mu;
  float rstd = rsqrtf(var + LN_EPS_);
  float4 o;
#pragma unroll
  for (int j = 0; j < 4; ++j) {
    int c = tid * 4 + j;
    (&o.x)[j] = gamma[c] * (x[j] - mu) * rstd + beta[c];
  }
  *(float4*)(out + (size_t)row * DM_ + tid * 4) = o;
}

// =====================================================================
extern "C" void kernel_launch(void* const* d_in, const int* in_sizes, int n_in,
                              void* d_out, int out_size, void* d_ws, size_t ws_size,
                              hipStream_t stream) {
  const float* h     = (const float*)d_in[0];
  const float* Wqkv  = (const float*)d_in[1];
  const float* Wo    = (const float*)d_in[2];
  const float* pi0   = (const float*)d_in[3];
  const float* gamma = (const float*)d_in[4];
  const float* beta  = (const float*)d_in[5];
  char* ws = (char*)d_ws;

  unsigned short* QKV   = (unsigned short*)ws;
  unsigned short* Sbuf  = (unsigned short*)(ws + 134217728ull);
  unsigned short* hb    = (unsigned short*)(ws + 134217728ull);   // dead after qkv_gemm
  unsigned short* Wqkvb = (unsigned short*)(ws + 167772160ull);   // dead after qkv_gemm
  unsigned short* Wob   = (unsigned short*)(ws + 201326592ull);
  unsigned short* LO    = (unsigned short*)ws;                    // overwrites q-part (dead)
  unsigned short* attn  = (unsigned short*)(ws + 134217728ull);   // overwrites Sbuf (dead after pv)
  float* X = (float*)d_out;

  dim3 blk(256);
  cvt_all<<<dim3(10752), blk, 0, stream>>>(h, Wqkv, Wo, hb, Wqkvb, Wob);
  qkv_gemm<<<dim3(16, 64, 1), dim3(512), 0, stream>>>(hb, Wqkvb, QKV);
  scores_kernel<<<dim3(3, 1, PAIRS_), blk, 0, stream>>>(QKV, pi0, Sbuf);
  pv_kernel<<<dim3(1, 2, PAIRS_), blk, 0, stream>>>(Sbuf, QKV + (size_t)3 * 16777216, LO);
  wo_gemm<<<dim3(4, 64, 1), dim3(512), 0, stream>>>(LO, Wob, attn);
  ln_res<<<dim3(ROWS_, 1, 1), blk, 0, stream>>>(attn, h, gamma, beta, X);
}